// Round 2
// baseline (153.960 us; speedup 1.0000x reference)
//
#include <hip/hip_runtime.h>
#include <hip/hip_bf16.h>

#define B 8
#define N 1024
#define IN 256
#define H 4
#define D 64
#define O 256   // H*D
#define BN (B*N)

typedef __attribute__((ext_vector_type(4))) float f32x4;
typedef __attribute__((ext_vector_type(8))) short short8;
typedef __attribute__((ext_vector_type(4))) short short4v;

__device__ __forceinline__ short f2bf(float f){
  __hip_bfloat16 b = __float2bfloat16(f);
  return __builtin_bit_cast(short, b);
}
__device__ __forceinline__ float bf2f(short s){
  unsigned u = ((unsigned)(unsigned short)s) << 16;
  return __builtin_bit_cast(float, u);
}

// Kernel 1: Wh = h @ W^T, written as bf16 VT[b][h][d][n]  (d-major, n contiguous)
// block = 256 threads (4 waves); block tile m=32, o=256 full.
// wave (w>>1) -> m-subtile of 16, (w&1) -> o-half of 128. grid = BN/32 = 256.
__global__ __launch_bounds__(256) void k_wh(const float* __restrict__ hmat,
                                            const float* __restrict__ Wmat,
                                            short* __restrict__ VT){
  const int t = threadIdx.x;
  const int wave = t >> 6, lane = t & 63, quad = lane >> 4, l16 = lane & 15;
  const int msub = blockIdx.x * 32 + (wave >> 1) * 16;
  const int obase = (wave & 1) * 128;
  f32x4 acc[8];
  #pragma unroll
  for(int x=0;x<8;x++) acc[x] = (f32x4){0.f,0.f,0.f,0.f};
  const float* ap = hmat + (size_t)(msub + l16) * IN + quad * 8;
  for(int k0 = 0; k0 < IN; k0 += 32){
    // A fragment: A[m=l16][k=quad*8+j], h row-major fp32 -> bf16
    float4 a0 = *(const float4*)(ap + k0);
    float4 a1 = *(const float4*)(ap + k0 + 4);
    short8 A;
    A[0]=f2bf(a0.x); A[1]=f2bf(a0.y); A[2]=f2bf(a0.z); A[3]=f2bf(a0.w);
    A[4]=f2bf(a1.x); A[5]=f2bf(a1.y); A[6]=f2bf(a1.z); A[7]=f2bf(a1.w);
    #pragma unroll
    for(int dt=0; dt<8; dt++){
      // B fragment: B[k][n] = W[n][k]  (Wh = h @ W^T)
      const float* bp = Wmat + (size_t)(obase + dt*16 + l16) * IN + k0 + quad*8;
      float4 b0 = *(const float4*)bp;
      float4 b1 = *(const float4*)(bp + 4);
      short8 Bf;
      Bf[0]=f2bf(b0.x); Bf[1]=f2bf(b0.y); Bf[2]=f2bf(b0.z); Bf[3]=f2bf(b0.w);
      Bf[4]=f2bf(b1.x); Bf[5]=f2bf(b1.y); Bf[6]=f2bf(b1.z); Bf[7]=f2bf(b1.w);
      acc[dt] = __builtin_amdgcn_mfma_f32_16x16x32_bf16(A, Bf, acc[dt], 0, 0, 0);
    }
  }
  // Epilogue: C row = quad*4+r (-> token), col = l16 (-> o). 4 consecutive tokens -> 8B store.
  const int bb = msub >> 10;              // batch index (32-row tiles never straddle b)
  const int nb = (msub & (N-1)) + quad * 4;
  #pragma unroll
  for(int dt=0; dt<8; dt++){
    int o = obase + dt*16 + l16;
    int hh = o >> 6, d = o & 63;
    short4v pk;
    pk[0]=f2bf(acc[dt][0]); pk[1]=f2bf(acc[dt][1]);
    pk[2]=f2bf(acc[dt][2]); pk[3]=f2bf(acc[dt][3]);
    *(short4v*)(VT + (((size_t)(bb*H + hh)*D + d) << 10) + nb) = pk;
  }
}

// Kernel 2: src[b,h,n] = sum_d VT[b,h,d,n]*a[h,d]; dst likewise with a[h,64+d].
__global__ __launch_bounds__(256) void k_srcdst(const short* __restrict__ VT,
                                                const float* __restrict__ avec,
                                                float* __restrict__ src,
                                                float* __restrict__ dst){
  int t = blockIdx.x * 256 + threadIdx.x;   // t = bh*1024 + n
  int bh = t >> 10, n = t & (N-1);
  int hh = bh & (H-1);
  const float* av = avec + hh * (2*D);      // uniform per block -> scalar loads
  const short* vp = VT + ((size_t)bh << 16) + n;
  float s = 0.f, dd = 0.f;
  #pragma unroll 8
  for(int d=0; d<D; d++){
    float v = bf2f(vp[(size_t)d << 10]);
    s  += v * av[d];
    dd += v * av[D + d];
  }
  src[t] = s; dst[t] = dd;
}

// Kernel 3: fused masked-softmax attention + PV via MFMA.
// block = 4 waves; wave w owns i-subtile of 16 (i = i0 + w*16 + (lane&15)), full d=64.
// j-loop tiles of 32: P fragment computed directly in A-layout registers;
// V tile staged d-major in LDS (stride 40 shorts = 80B, 16B-aligned rows).
// adj_mask is numpy bool -> harness ships it as int32 (one int per element).
__global__ __launch_bounds__(256) void k_attn(const short* __restrict__ VT,
                                              const float* __restrict__ src,
                                              const float* __restrict__ dst,
                                              const int* __restrict__ adj,
                                              float* __restrict__ out){
  __shared__ float dsh[N];
  __shared__ short vt[D * 40];
  __shared__ float lsh[4][16];
  const int t = threadIdx.x;
  const int wave = t >> 6, lane = t & 63, quad = lane >> 4, l16 = lane & 15;
  const int b = blockIdx.z, hh = blockIdx.y;
  const int bh = b * H + hh;
  const int i0 = blockIdx.x * 64;
  for(int j = t; j < N; j += 256) dsh[j] = dst[(size_t)bh * N + j];
  const int i = i0 + wave * 16 + l16;       // row owned by this lane (all quads)
  const float si = src[(size_t)bh * N + i];
  const int* adjrow = adj + ((size_t)b * N + i) * N;
  const int sd = t >> 2;                    // staging: d row
  const int sc = (t & 3) * 8;               // staging: j chunk
  const short* vsrc = VT + (((size_t)bh * D + sd) << 10) + sc;
  f32x4 acc[4];
  #pragma unroll
  for(int x=0;x<4;x++) acc[x] = (f32x4){0.f,0.f,0.f,0.f};
  float lsum = 0.f;
  for(int j0 = 0; j0 < N; j0 += 32){
    __syncthreads();                         // iter0: dsh ready; else: vt reuse guard
    *(short8*)&vt[sd * 40 + sc] = *(const short8*)(vsrc + j0);
    __syncthreads();
    const int4* amp = (const int4*)(adjrow + j0 + quad * 8);
    int4 m0 = amp[0], m1 = amp[1];
    int msk[8] = {m0.x, m0.y, m0.z, m0.w, m1.x, m1.y, m1.z, m1.w};
    short8 P;
    #pragma unroll
    for(int jj=0; jj<8; jj++){
      float e = si + dsh[j0 + quad*8 + jj];
      e = e > 0.f ? e : 0.2f * e;            // leaky_relu 0.2
      // no max-subtraction needed: e <= ~8, exp safely in fp32
      float p = msk[jj] ? __expf(e) : 0.f;
      P[jj] = f2bf(p);
      lsum += bf2f(P[jj]);                   // denominator from the value MFMA uses
    }
    #pragma unroll
    for(int dt=0; dt<4; dt++){
      short8 Bf = *(const short8*)&vt[(dt*16 + l16) * 40 + quad*8];
      acc[dt] = __builtin_amdgcn_mfma_f32_16x16x32_bf16(P, Bf, acc[dt], 0, 0, 0);
    }
  }
  // row-sum l: partials live per-quad for the same row (lane bits 4,5)
  lsum += __shfl_xor(lsum, 16, 64);
  lsum += __shfl_xor(lsum, 32, 64);
  if(quad == 0) lsh[wave][l16] = lsum;
  __syncthreads();
  #pragma unroll
  for(int dt=0; dt<4; dt++){
    #pragma unroll
    for(int r=0; r<4; r++){
      int irow = quad * 4 + r;               // C row = quad*4+reg
      float inv = 1.0f / lsh[wave][irow];
      int ig = i0 + wave * 16 + irow;
      out[((size_t)b * N + ig) * O + hh * D + dt * 16 + l16] = acc[dt][r] * inv;
    }
  }
}

extern "C" void kernel_launch(void* const* d_in, const int* in_sizes, int n_in,
                              void* d_out, int out_size, void* d_ws, size_t ws_size,
                              hipStream_t stream) {
  const float* hmat = (const float*)d_in[0];
  const float* Wmat = (const float*)d_in[1];
  const float* avec = (const float*)d_in[2];
  const int* adj    = (const int*)d_in[3];   // bool -> int32 per harness convention
  float* out = (float*)d_out;
  short* VT  = (short*)d_ws;                                  // 4 MB bf16 Wh^T
  float* src = (float*)((char*)d_ws + (size_t)4*1024*1024);   // 128 KB
  float* dst = src + (size_t)B*H*N;                           // 128 KB
  k_wh<<<BN/32, 256, 0, stream>>>(hmat, Wmat, VT);
  k_srcdst<<<(B*H*N)/256, 256, 0, stream>>>(VT, avec, src, dst);
  k_attn<<<dim3(N/64, H, B), 256, 0, stream>>>(VT, src, dst, adj, out);
}

// Round 3
// 138.107 us; speedup vs baseline: 1.1148x; 1.1148x over previous
//
#include <hip/hip_runtime.h>
#include <hip/hip_bf16.h>

#define B 8
#define N 1024
#define IN 256
#define H 4
#define D 64
#define O 256   // H*D
#define BN (B*N)

typedef __attribute__((ext_vector_type(4))) float f32x4;
typedef __attribute__((ext_vector_type(8))) short short8;
typedef __attribute__((ext_vector_type(4))) short short4v;

__device__ __forceinline__ short f2bf(float f){
  __hip_bfloat16 b = __float2bfloat16(f);
  return __builtin_bit_cast(short, b);
}
__device__ __forceinline__ float bf2f(short s){
  unsigned u = ((unsigned)(unsigned short)s) << 16;
  return __builtin_bit_cast(float, u);
}

// ---------------------------------------------------------------------------
// k_prep: (a) pack adj int32 -> bitmask words  (b) convert h, W fp32 -> bf16.
// pack: 1024 blocks, thread t handles 32 consecutive ints -> 1 word (base = t*32).
// cvt: 1056 blocks, thread handles 8 floats.
// ---------------------------------------------------------------------------
#define PACK_BLOCKS 1024
#define CVT_BLOCKS  1056
#define H_ELEMS (BN*IN)          // 2097152
__global__ __launch_bounds__(256) void k_prep(const int* __restrict__ adj,
                                              unsigned* __restrict__ bits,
                                              const float* __restrict__ hmat,
                                              const float* __restrict__ Wmat,
                                              short* __restrict__ hbf,
                                              short* __restrict__ wbf){
  if(blockIdx.x < PACK_BLOCKS){
    int t = blockIdx.x * 256 + threadIdx.x;          // [0, 262144)
    const int4* p = (const int4*)(adj + ((size_t)t << 5));
    unsigned word = 0;
    #pragma unroll
    for(int k = 0; k < 8; k++){
      int4 m = p[k];
      word |= (m.x != 0 ? 1u : 0u) << (k*4 + 0);
      word |= (m.y != 0 ? 1u : 0u) << (k*4 + 1);
      word |= (m.z != 0 ? 1u : 0u) << (k*4 + 2);
      word |= (m.w != 0 ? 1u : 0u) << (k*4 + 3);
    }
    bits[t] = word;
  } else {
    int idx = (blockIdx.x - PACK_BLOCKS) * 256 + threadIdx.x;  // [0, 270336)
    int e = idx * 8;
    const float* srcp; short* dstp;
    if(e < H_ELEMS){ srcp = hmat + e; dstp = hbf + e; }
    else           { srcp = Wmat + (e - H_ELEMS); dstp = wbf + (e - H_ELEMS); }
    float4 a0 = *(const float4*)srcp;
    float4 a1 = *(const float4*)(srcp + 4);
    short8 pk;
    pk[0]=f2bf(a0.x); pk[1]=f2bf(a0.y); pk[2]=f2bf(a0.z); pk[3]=f2bf(a0.w);
    pk[4]=f2bf(a1.x); pk[5]=f2bf(a1.y); pk[6]=f2bf(a1.z); pk[7]=f2bf(a1.w);
    *(short8*)dstp = pk;
  }
}

// ---------------------------------------------------------------------------
// k_wh: Wh = h @ W^T from pre-converted bf16; writes VT[b][h][d][n] (bf16) and
// fused src/dst epilogue (from fp32 acc, more accurate than bf16 round-trip).
// grid 512 blocks x 256: block = m-tile 16; wave w = head w (o range 64).
// ---------------------------------------------------------------------------
__global__ __launch_bounds__(256) void k_wh(const short* __restrict__ hbf,
                                            const short* __restrict__ wbf,
                                            const float* __restrict__ avec,
                                            short* __restrict__ VT,
                                            float* __restrict__ src,
                                            float* __restrict__ dst){
  const int t = threadIdx.x;
  const int hh = t >> 6, lane = t & 63, quad = lane >> 4, l16 = lane & 15;
  const int mbase = blockIdx.x * 16;
  f32x4 acc[4];
  #pragma unroll
  for(int x=0;x<4;x++) acc[x] = (f32x4){0.f,0.f,0.f,0.f};
  const short* ap = hbf + (size_t)(mbase + l16) * IN + quad * 8;
  const short* bp0 = wbf + (size_t)(hh * 64 + l16) * IN + quad * 8;
  #pragma unroll
  for(int kk = 0; kk < 8; kk++){
    const int k0 = kk * 32;
    short8 A = *(const short8*)(ap + k0);
    #pragma unroll
    for(int dt=0; dt<4; dt++){
      short8 Bf = *(const short8*)(bp0 + (size_t)dt*16*IN + k0);
      acc[dt] = __builtin_amdgcn_mfma_f32_16x16x32_bf16(A, Bf, acc[dt], 0, 0, 0);
    }
  }
  // ---- epilogue 1: store bf16 VT.  C row = quad*4+r -> token n, col l16 -> d.
  const int bb = mbase >> 10;
  const int nb = (mbase & (N-1)) + quad * 4;
  const int bh = bb * H + hh;
  #pragma unroll
  for(int dt=0; dt<4; dt++){
    int d = dt*16 + l16;
    short4v pk;
    pk[0]=f2bf(acc[dt][0]); pk[1]=f2bf(acc[dt][1]);
    pk[2]=f2bf(acc[dt][2]); pk[3]=f2bf(acc[dt][3]);
    *(short4v*)(VT + (((size_t)bh * D + d) << 10) + nb) = pk;
  }
  // ---- epilogue 2: fused src/dst  (src = Wh . a[:,:64], dst = Wh . a[:,64:])
  float as[4], ad[4];
  #pragma unroll
  for(int dt=0; dt<4; dt++){
    as[dt] = avec[hh*(2*D) + dt*16 + l16];
    ad[dt] = avec[hh*(2*D) + D + dt*16 + l16];
  }
  #pragma unroll
  for(int r=0; r<4; r++){
    float s = 0.f, dd = 0.f;
    #pragma unroll
    for(int dt=0; dt<4; dt++){ s += acc[dt][r]*as[dt]; dd += acc[dt][r]*ad[dt]; }
    #pragma unroll
    for(int off=1; off<16; off<<=1){
      s  += __shfl_xor(s, off, 64);
      dd += __shfl_xor(dd, off, 64);
    }
    if(l16 == 0){
      int n = nb + r;
      src[(size_t)bh * N + n] = s;
      dst[(size_t)bh * N + n] = dd;
    }
  }
}

// ---------------------------------------------------------------------------
// k_attn: barrier-free masked-softmax + PV.  grid dim3(32, H, B):
// ib = x>>1 (i-tile of 64), jc = x&1 (j-range 512).  4096 waves total.
// Mask bits preloaded to 16 VGPRs; B-frags loaded straight from global VT
// (d-major => fragment = 16 contiguous bytes, L2-hot); dst row in LDS (1 barrier).
// Writes fp32 partial acc + partial lsum; k_combine finishes.
// ---------------------------------------------------------------------------
__global__ __launch_bounds__(256) void k_attn(const short* __restrict__ VT,
                                              const float* __restrict__ src,
                                              const float* __restrict__ dst,
                                              const unsigned* __restrict__ bits,
                                              float* __restrict__ pacc,
                                              float* __restrict__ plsum){
  __shared__ float dsh[512];
  const int t = threadIdx.x;
  const int wave = t >> 6, lane = t & 63, quad = lane >> 4, l16 = lane & 15;
  const int b = blockIdx.z, hh = blockIdx.y;
  const int bh = b * H + hh;
  const int ib = blockIdx.x >> 1, jc = blockIdx.x & 1;
  const int i0 = ib * 64, jbase = jc * 512;
  #pragma unroll
  for(int j = t; j < 512; j += 256) dsh[j] = dst[(size_t)bh * N + jbase + j];
  const int i = i0 + wave * 16 + l16;
  const float si = src[(size_t)bh * N + i];
  // preload this row's 512 mask bits (16 words)
  const int4* mp = (const int4*)(bits + ((size_t)b * N + i) * 32 + jc * 16);
  int4 mv0 = mp[0], mv1 = mp[1], mv2 = mp[2], mv3 = mp[3];
  unsigned mw[16] = {(unsigned)mv0.x,(unsigned)mv0.y,(unsigned)mv0.z,(unsigned)mv0.w,
                     (unsigned)mv1.x,(unsigned)mv1.y,(unsigned)mv1.z,(unsigned)mv1.w,
                     (unsigned)mv2.x,(unsigned)mv2.y,(unsigned)mv2.z,(unsigned)mv2.w,
                     (unsigned)mv3.x,(unsigned)mv3.y,(unsigned)mv3.z,(unsigned)mv3.w};
  const short* vrow = VT + (((size_t)bh * D) << 10) + jbase + quad * 8;
  f32x4 acc[4];
  #pragma unroll
  for(int x=0;x<4;x++) acc[x] = (f32x4){0.f,0.f,0.f,0.f};
  float lsum = 0.f;
  __syncthreads();
  #pragma unroll
  for(int jt = 0; jt < 16; jt++){
    const int j0 = jt * 32;
    const unsigned word = mw[jt];
    float4 d0 = *(const float4*)&dsh[j0 + quad*8];
    float4 d1 = *(const float4*)&dsh[j0 + quad*8 + 4];
    float dv[8] = {d0.x,d0.y,d0.z,d0.w,d1.x,d1.y,d1.z,d1.w};
    short8 P;
    #pragma unroll
    for(int jj=0; jj<8; jj++){
      float e = si + dv[jj];
      e = fmaxf(e, 0.2f * e);                          // leaky_relu(0.2)
      float p = ((word >> (quad*8 + jj)) & 1u) ? __expf(e) : 0.f;
      P[jj] = f2bf(p);
      lsum += bf2f(P[jj]);                             // denom = what MFMA sees
    }
    #pragma unroll
    for(int dt=0; dt<4; dt++){
      short8 Bf = *(const short8*)(vrow + (((size_t)(dt*16 + l16)) << 10) + j0);
      acc[dt] = __builtin_amdgcn_mfma_f32_16x16x32_bf16(P, Bf, acc[dt], 0, 0, 0);
    }
  }
  // reduce lsum across the 4 quads (same row)
  lsum += __shfl_xor(lsum, 16, 64);
  lsum += __shfl_xor(lsum, 32, 64);
  const int pslot = bh * 2 + jc;
  if(quad == 0) plsum[(size_t)pslot * N + i] = lsum;
  // store raw fp32 partial acc: pacc[pslot][ig][d]
  float* pa = pacc + ((size_t)pslot << 16);
  #pragma unroll
  for(int dt=0; dt<4; dt++){
    #pragma unroll
    for(int r=0; r<4; r++){
      int ig = i0 + wave*16 + quad*4 + r;
      pa[(ig << 6) + dt*16 + l16] = acc[dt][r];
    }
  }
}

// ---------------------------------------------------------------------------
// k_combine: out[b][n][h*64+d] = (p0+p1)/(l0+l1)
// ---------------------------------------------------------------------------
__global__ __launch_bounds__(256) void k_combine(const float* __restrict__ pacc,
                                                 const float* __restrict__ plsum,
                                                 float* __restrict__ out){
  int t = blockIdx.x * 256 + threadIdx.x;    // [0, B*N*O)
  int o = t & 255, n = (t >> 8) & (N-1), b = t >> 18;
  int hh = o >> 6, d = o & 63;
  int slot = (b * H + hh) * 2;
  size_t base = ((size_t)slot << 16) + (n << 6) + d;
  float p = pacc[base] + pacc[base + 65536];
  float l = plsum[(size_t)slot * N + n] + plsum[(size_t)(slot+1) * N + n];
  out[t] = p / l;
}

extern "C" void kernel_launch(void* const* d_in, const int* in_sizes, int n_in,
                              void* d_out, int out_size, void* d_ws, size_t ws_size,
                              hipStream_t stream) {
  const float* hmat = (const float*)d_in[0];
  const float* Wmat = (const float*)d_in[1];
  const float* avec = (const float*)d_in[2];
  const int* adj    = (const int*)d_in[3];   // numpy bool -> int32 per harness
  float* out = (float*)d_out;
  char* ws = (char*)d_ws;
  short*    VT    = (short*)   (ws);                         //  4 MB
  short*    hbf   = (short*)   (ws + (size_t) 4*1024*1024);  //  4 MB
  short*    wbf   = (short*)   (ws + (size_t) 8*1024*1024);  //  128 KB
  unsigned* bits  = (unsigned*)(ws + (size_t) 9*1024*1024);  //  1 MB
  float*    src   = (float*)   (ws + (size_t)10*1024*1024);  //  128 KB
  float*    dst   = (float*)   (ws + (size_t)10*1024*1024 + 131072);
  float*    plsum = (float*)   (ws + (size_t)11*1024*1024);  //  256 KB
  float*    pacc  = (float*)   (ws + (size_t)12*1024*1024);  //  16 MB
  k_prep<<<PACK_BLOCKS + CVT_BLOCKS, 256, 0, stream>>>(adj, bits, hmat, Wmat, hbf, wbf);
  k_wh<<<BN/16, 256, 0, stream>>>(hbf, wbf, avec, VT, src, dst);
  k_attn<<<dim3(32, H, B), 256, 0, stream>>>(VT, src, dst, bits, pacc, plsum);
  k_combine<<<(BN*O)/256, 256, 0, stream>>>(pacc, plsum, out);
}